// Round 1
// baseline (2394.279 us; speedup 1.0000x reference)
//
#include <hip/hip_runtime.h>
#include <stdint.h>

typedef unsigned short u16;
typedef __bf16  bf16x8 __attribute__((ext_vector_type(8)));
typedef float   f32x4  __attribute__((ext_vector_type(4)));

#define DEVINL __device__ __forceinline__

// ---------- helpers ----------
DEVINL u16 f2bf(float f) {                       // RNE float->bf16
    union { float f; uint32_t u; } v; v.f = f;
    uint32_t r = v.u + 0x7fffu + ((v.u >> 16) & 1u);
    return (u16)(r >> 16);
}

DEVINL float gelu_exact(float x) {               // x * Phi(x), exact erf
    return 0.5f * x * (1.0f + erff(x * 0.70710678118654752f));
}

// async global->LDS, 16 B per lane. LDS dest must be wave-uniform base.
typedef const void __attribute__((address_space(1))) gvoid;
typedef void __attribute__((address_space(3))) lvoid;
DEVINL void gload_lds16(const u16* g, u16* l) {
    __builtin_amdgcn_global_load_lds((gvoid*)g, (lvoid*)l, 16, 0, 0);
}

// ---------- transpose + fp32->bf16 convert:  W[K][N] -> Wt[N][K] ----------
__global__ __launch_bounds__(256) void k_transpose_conv(
    const float* __restrict__ W, u16* __restrict__ Wt, int K, int N) {
    __shared__ float t[32][33];
    const int n0 = blockIdx.x * 32, k0 = blockIdx.y * 32;
    const int tx = threadIdx.x & 31, ty = threadIdx.x >> 5;   // ty 0..7
#pragma unroll
    for (int i = 0; i < 4; i++)
        t[ty + i * 8][tx] = W[(size_t)(k0 + ty + i * 8) * N + n0 + tx];
    __syncthreads();
#pragma unroll
    for (int i = 0; i < 4; i++)
        Wt[(size_t)(n0 + ty + i * 8) * K + k0 + tx] = f2bf(t[tx][ty + i * 8]);
}

// ---------- LayerNorm over C=1024, fp32 in -> bf16 out ----------
__global__ __launch_bounds__(256) void k_layernorm(
    const float* __restrict__ x, const float* __restrict__ g,
    const float* __restrict__ b, u16* __restrict__ out) {
    const int row = blockIdx.x, tid = threadIdx.x;
    float4 v = ((const float4*)x)[(size_t)row * 256 + tid];
    float s  = v.x + v.y + v.z + v.w;
    float s2 = v.x * v.x + v.y * v.y + v.z * v.z + v.w * v.w;
#pragma unroll
    for (int off = 32; off > 0; off >>= 1) {
        s  += __shfl_down(s, off);
        s2 += __shfl_down(s2, off);
    }
    __shared__ float rs[4], rs2[4];
    const int wv = tid >> 6;
    if ((tid & 63) == 0) { rs[wv] = s; rs2[wv] = s2; }
    __syncthreads();
    s  = rs[0] + rs[1] + rs[2] + rs[3];
    s2 = rs2[0] + rs2[1] + rs2[2] + rs2[3];
    const float mu  = s * (1.0f / 1024.0f);
    const float var = s2 * (1.0f / 1024.0f) - mu * mu;
    const float rstd = rsqrtf(var + 1e-5f);
    float4 gv = ((const float4*)g)[tid];
    float4 bv = ((const float4*)b)[tid];
    uint2 o;
    u16 a0 = f2bf((v.x - mu) * rstd * gv.x + bv.x);
    u16 a1 = f2bf((v.y - mu) * rstd * gv.y + bv.y);
    u16 a2 = f2bf((v.z - mu) * rstd * gv.z + bv.z);
    u16 a3 = f2bf((v.w - mu) * rstd * gv.w + bv.w);
    o.x = a0 | ((uint32_t)a1 << 16);
    o.y = a2 | ((uint32_t)a3 << 16);
    ((uint2*)out)[(size_t)row * 256 + tid] = o;
}

// ---------- bf16 GEMM: C[M,N] = A[M,K] * Bt[N,K]^T, fused epilogues ----------
enum { EPI_BF16 = 0, EPI_F32_BIAS_RES = 1, EPI_BF16_BIAS_GELU = 2 };

template <int EPI>
__global__ __launch_bounds__(256) void k_gemm_bt(
    const u16* __restrict__ A, const u16* __restrict__ Bt,
    void* outp, const float* __restrict__ bias, const float* res,
    int N, int K) {
    __shared__ __align__(16) u16 As[128 * 32];   // [row][k] row-major
    __shared__ __align__(16) u16 Bs[128 * 32];   // [col][k] row-major (Bt tile)
    const int tid  = threadIdx.x;
    const int lane = tid & 63, wv = tid >> 6;
    const int wm = wv >> 1, wn = wv & 1;          // 2x2 wave grid, 64x64 per wave
    const int lr = lane >> 2, lc = (lane & 3) * 8;
    const int c0 = wv * 2;                        // LDS chunk index (16 rows / 1KB each)
    const size_t aRow0 = (size_t)blockIdx.y * 128;
    const size_t bRow0 = (size_t)blockIdx.x * 128;

    f32x4 acc[4][4] = {};
    const int mrow = lane & 15;
    const int koff = (lane >> 4) * 8;
    const int kIters = K >> 5;

    for (int kt = 0; kt < kIters; kt++) {
        const int k0 = kt << 5;
        gload_lds16(A  + (aRow0 + (size_t)(c0 * 16      + lr)) * K + k0 + lc, &As[c0 * 512]);
        gload_lds16(A  + (aRow0 + (size_t)(c0 * 16 + 16 + lr)) * K + k0 + lc, &As[(c0 + 1) * 512]);
        gload_lds16(Bt + (bRow0 + (size_t)(c0 * 16      + lr)) * K + k0 + lc, &Bs[c0 * 512]);
        gload_lds16(Bt + (bRow0 + (size_t)(c0 * 16 + 16 + lr)) * K + k0 + lc, &Bs[(c0 + 1) * 512]);
        __syncthreads();
        bf16x8 af[4], bfv[4];
#pragma unroll
        for (int i = 0; i < 4; i++)
            af[i] = *(const bf16x8*)&As[(wm * 64 + i * 16 + mrow) * 32 + koff];
#pragma unroll
        for (int i = 0; i < 4; i++)
            bfv[i] = *(const bf16x8*)&Bs[(wn * 64 + i * 16 + mrow) * 32 + koff];
#pragma unroll
        for (int mi = 0; mi < 4; mi++)
#pragma unroll
            for (int ni = 0; ni < 4; ni++)
                acc[mi][ni] = __builtin_amdgcn_mfma_f32_16x16x32_bf16(
                    af[mi], bfv[ni], acc[mi][ni], 0, 0, 0);
        __syncthreads();
    }

    // epilogue — C/D layout: col = lane&15, row = (lane>>4)*4 + reg
    const int rr = (lane >> 4) * 4;
    const int cc = lane & 15;
#pragma unroll
    for (int mi = 0; mi < 4; mi++) {
#pragma unroll
        for (int ni = 0; ni < 4; ni++) {
#pragma unroll
            for (int r = 0; r < 4; r++) {
                const size_t row = aRow0 + wm * 64 + mi * 16 + rr + r;
                const size_t col = bRow0 + wn * 64 + ni * 16 + cc;
                const float v = acc[mi][ni][r];
                if (EPI == EPI_BF16) {
                    ((u16*)outp)[row * N + col] = f2bf(v);
                } else if (EPI == EPI_F32_BIAS_RES) {
                    ((float*)outp)[row * N + col] = res[row * N + col] + v + bias[col];
                } else {
                    ((u16*)outp)[row * N + col] = f2bf(gelu_exact(v + bias[col]));
                }
            }
        }
    }
}

// ---------- V transpose: qkv v-part [b,n,(h,d)] -> vT[(b,h),d,n] ----------
__global__ __launch_bounds__(256) void k_vtrans(
    const u16* __restrict__ qkv, u16* __restrict__ vT) {
    __shared__ u16 t[32][33];
    const int bh = blockIdx.z;                 // b*16+h
    const int b = bh >> 4, h = bh & 15;
    const int n0 = blockIdx.x * 32, d0 = blockIdx.y * 32;
    const int tx = threadIdx.x & 31, ty = threadIdx.x >> 5;
#pragma unroll
    for (int i = 0; i < 4; i++)
        t[ty + i * 8][tx] = qkv[(size_t)(b * 1024 + n0 + ty + i * 8) * 3072 + 2048 + h * 64 + d0 + tx];
    __syncthreads();
#pragma unroll
    for (int i = 0; i < 4; i++)
        vT[(size_t)(bh * 64 + d0 + ty + i * 8) * 1024 + n0 + tx] = t[tx][ty + i * 8];
}

// ---------- flash attention, bf16 MFMA, online softmax ----------
// grid (N/64, H, B); block 256 = 4 waves; each wave owns 16 q rows.
__global__ __launch_bounds__(256) void k_attention(
    const u16* __restrict__ qkv, const u16* __restrict__ vT, u16* __restrict__ o) {
    const int qt = blockIdx.x, h = blockIdx.y, b = blockIdx.z;
    const int tid = threadIdx.x;
    const int lane = tid & 63, wv = tid >> 6;
    const int quad = lane >> 4, l16 = lane & 15;
    __shared__ __align__(16) u16 Ks[64 * 64];      // [j][d]
    __shared__ __align__(16) u16 Vs[64 * 64];      // [d][j]  (transposed V)
    __shared__ __align__(16) u16 Ps[4][16 * 64];   // per-wave P [qrow][j]
    const int q0 = qt * 64 + wv * 16;

    bf16x8 qa[2];
    {
        const u16* qp = qkv + (size_t)(b * 1024 + q0 + l16) * 3072 + h * 64 + quad * 8;
        qa[0] = *(const bf16x8*)qp;
        qa[1] = *(const bf16x8*)(qp + 32);
    }
    f32x4 oacc[4] = {};
    float mst[4], lst[4];
#pragma unroll
    for (int r = 0; r < 4; r++) { mst[r] = -__builtin_inff(); lst[r] = 0.f; }

    const int tr = tid >> 3, tc = (tid & 7) * 8;
    const size_t kvbase = (size_t)(b * 1024) * 3072 + 1024 + h * 64;
    const size_t vtbase = (size_t)(b * 16 + h) * 64 * 1024;

    for (int j0 = 0; j0 < 1024; j0 += 64) {
        *(uint4*)&Ks[tr * 64 + tc]        = *(const uint4*)&qkv[kvbase + (size_t)(j0 + tr) * 3072 + tc];
        *(uint4*)&Ks[(tr + 32) * 64 + tc] = *(const uint4*)&qkv[kvbase + (size_t)(j0 + tr + 32) * 3072 + tc];
        *(uint4*)&Vs[tr * 64 + tc]        = *(const uint4*)&vT[vtbase + (size_t)tr * 1024 + j0 + tc];
        *(uint4*)&Vs[(tr + 32) * 64 + tc] = *(const uint4*)&vT[vtbase + (size_t)(tr + 32) * 1024 + j0 + tc];
        __syncthreads();

        // S = Q K^T  (16 qrows x 64 j per wave)
        f32x4 s[4] = {};
#pragma unroll
        for (int nt = 0; nt < 4; nt++) {
            bf16x8 kb0 = *(const bf16x8*)&Ks[(nt * 16 + l16) * 64 + quad * 8];
            bf16x8 kb1 = *(const bf16x8*)&Ks[(nt * 16 + l16) * 64 + quad * 8 + 32];
            s[nt] = __builtin_amdgcn_mfma_f32_16x16x32_bf16(qa[0], kb0, s[nt], 0, 0, 0);
            s[nt] = __builtin_amdgcn_mfma_f32_16x16x32_bf16(qa[1], kb1, s[nt], 0, 0, 0);
        }
        // online softmax, rows quad*4+r, 16 lanes per row
#pragma unroll
        for (int r = 0; r < 4; r++) {
            float v0 = s[0][r] * 0.03125f, v1 = s[1][r] * 0.03125f;
            float v2 = s[2][r] * 0.03125f, v3 = s[3][r] * 0.03125f;
            float mx = fmaxf(fmaxf(v0, v1), fmaxf(v2, v3));
#pragma unroll
            for (int off = 1; off < 16; off <<= 1) mx = fmaxf(mx, __shfl_xor(mx, off));
            const float mnew = fmaxf(mst[r], mx);
            const float alpha = __expf(mst[r] - mnew);
            mst[r] = mnew;
            const float p0 = __expf(v0 - mnew), p1 = __expf(v1 - mnew);
            const float p2 = __expf(v2 - mnew), p3 = __expf(v3 - mnew);
            float rsum = p0 + p1 + p2 + p3;
#pragma unroll
            for (int off = 1; off < 16; off <<= 1) rsum += __shfl_xor(rsum, off);
            lst[r] = lst[r] * alpha + rsum;
#pragma unroll
            for (int dt = 0; dt < 4; dt++) oacc[dt][r] *= alpha;
            u16* pr = &Ps[wv][(quad * 4 + r) * 64 + l16];
            pr[0]  = f2bf(p0); pr[16] = f2bf(p1);
            pr[32] = f2bf(p2); pr[48] = f2bf(p3);
        }
        __syncthreads();
        // O += P V   (A = P via LDS round-trip, B = V from transposed tile)
        bf16x8 pa0 = *(const bf16x8*)&Ps[wv][l16 * 64 + quad * 8];
        bf16x8 pa1 = *(const bf16x8*)&Ps[wv][l16 * 64 + quad * 8 + 32];
#pragma unroll
        for (int dt = 0; dt < 4; dt++) {
            bf16x8 vb0 = *(const bf16x8*)&Vs[(dt * 16 + l16) * 64 + quad * 8];
            bf16x8 vb1 = *(const bf16x8*)&Vs[(dt * 16 + l16) * 64 + quad * 8 + 32];
            oacc[dt] = __builtin_amdgcn_mfma_f32_16x16x32_bf16(pa0, vb0, oacc[dt], 0, 0, 0);
            oacc[dt] = __builtin_amdgcn_mfma_f32_16x16x32_bf16(pa1, vb1, oacc[dt], 0, 0, 0);
        }
        __syncthreads();
    }
#pragma unroll
    for (int dt = 0; dt < 4; dt++)
#pragma unroll
        for (int r = 0; r < 4; r++) {
            const float v = oacc[dt][r] / lst[r];
            o[(size_t)(b * 1024 + q0 + quad * 4 + r) * 1024 + h * 64 + dt * 16 + l16] = f2bf(v);
        }
}

// ---------- host ----------
extern "C" void kernel_launch(void* const* d_in, const int* in_sizes, int n_in,
                              void* d_out, int out_size, void* d_ws, size_t ws_size,
                              hipStream_t stream) {
    const float* x_in = (const float*)d_in[0];
    const float* Wqkv = (const float*)d_in[1];
    const float* Wout = (const float*)d_in[2];
    const float* bout = (const float*)d_in[3];
    const float* W1   = (const float*)d_in[4];
    const float* b1   = (const float*)d_in[5];
    const float* W2   = (const float*)d_in[6];
    const float* b2   = (const float*)d_in[7];
    const float* ln1g = (const float*)d_in[8];
    const float* ln1b = (const float*)d_in[9];
    const float* ln2g = (const float*)d_in[10];
    const float* ln2b = (const float*)d_in[11];
    float* xbuf = (float*)d_out;

    char* p = (char*)d_ws;
    auto carve = [&](size_t elems) -> u16* {
        u16* r = (u16*)p;
        p += ((elems * 2 + 255) & ~(size_t)255);
        return r;
    };
    u16* wq   = carve((size_t)3072 * 1024);   // per-layer Wqkv^T bf16
    u16* wo   = carve((size_t)1024 * 1024);   // per-layer Wout^T
    u16* w1t  = carve((size_t)4096 * 1024);   // per-layer W1^T
    u16* w2t  = carve((size_t)1024 * 4096);   // per-layer W2^T
    u16* hb   = carve((size_t)4096 * 1024);   // LN output bf16
    u16* qkvb = carve((size_t)4096 * 3072);   // qkv bf16
    u16* vtb  = carve((size_t)4096 * 1024);   // V^T bf16 [(b,h),d,n]
    u16* ob   = carve((size_t)4096 * 1024);   // attention out bf16
    u16* gb   = carve((size_t)4096 * 4096);   // gelu(ffn1) bf16
    if ((size_t)(p - (char*)d_ws) > ws_size) return;  // ws too small -> clean fail

    hipMemcpyAsync(xbuf, x_in, (size_t)4096 * 1024 * 4, hipMemcpyDeviceToDevice, stream);

    for (int l = 0; l < 6; l++) {
        k_transpose_conv<<<dim3(96, 32), 256, 0, stream>>>(Wqkv + (size_t)l * 1024 * 3072, wq, 1024, 3072);
        k_transpose_conv<<<dim3(32, 32), 256, 0, stream>>>(Wout + (size_t)l * 1024 * 1024, wo, 1024, 1024);
        k_transpose_conv<<<dim3(128, 32), 256, 0, stream>>>(W1 + (size_t)l * 1024 * 4096, w1t, 1024, 4096);
        k_transpose_conv<<<dim3(32, 128), 256, 0, stream>>>(W2 + (size_t)l * 4096 * 1024, w2t, 4096, 1024);

        k_layernorm<<<4096, 256, 0, stream>>>(xbuf, ln1g, ln1b, hb);
        k_gemm_bt<EPI_BF16><<<dim3(24, 32), 256, 0, stream>>>(hb, wq, qkvb, nullptr, nullptr, 3072, 1024);
        k_vtrans<<<dim3(32, 2, 64), 256, 0, stream>>>(qkvb, vtb);
        k_attention<<<dim3(16, 16, 4), 256, 0, stream>>>(qkvb, vtb, ob);
        k_gemm_bt<EPI_F32_BIAS_RES><<<dim3(8, 32), 256, 0, stream>>>(ob, wo, xbuf, bout + (size_t)l * 1024, xbuf, 1024, 1024);
        k_layernorm<<<4096, 256, 0, stream>>>(xbuf, ln2g, ln2b, hb);
        k_gemm_bt<EPI_BF16_BIAS_GELU><<<dim3(32, 32), 256, 0, stream>>>(hb, w1t, gb, b1 + (size_t)l * 4096, nullptr, 4096, 1024);
        k_gemm_bt<EPI_F32_BIAS_RES><<<dim3(8, 32), 256, 0, stream>>>(gb, w2t, xbuf, b2 + (size_t)l * 1024, xbuf, 1024, 4096);
    }
}

// Round 3
// 2256.219 us; speedup vs baseline: 1.0612x; 1.0612x over previous
//
#include <hip/hip_runtime.h>
#include <stdint.h>

typedef unsigned short u16;
typedef __bf16  bf16x8 __attribute__((ext_vector_type(8)));
typedef float   f32x4  __attribute__((ext_vector_type(4)));

#define DEVINL __device__ __forceinline__

// ---------- helpers ----------
DEVINL u16 f2bf(float f) {                       // RNE float->bf16
    union { float f; uint32_t u; } v; v.f = f;
    uint32_t r = v.u + 0x7fffu + ((v.u >> 16) & 1u);
    return (u16)(r >> 16);
}

DEVINL float gelu_exact(float x) {               // x * Phi(x), exact erf
    return 0.5f * x * (1.0f + erff(x * 0.70710678118654752f));
}

// async global->LDS, 16 B per lane. LDS dest must be wave-uniform base.
typedef const void __attribute__((address_space(1))) gvoid;
typedef void __attribute__((address_space(3))) lvoid;
DEVINL void gload_lds16(const u16* g, u16* l) {
    __builtin_amdgcn_global_load_lds((gvoid*)g, (lvoid*)l, 16, 0, 0);
}

// ---------- transpose + fp32->bf16 convert:  W[K][N] -> Wt[N][K] ----------
__global__ __launch_bounds__(256) void k_transpose_conv(
    const float* __restrict__ W, u16* __restrict__ Wt, int K, int N) {
    __shared__ float t[32][33];
    const int n0 = blockIdx.x * 32, k0 = blockIdx.y * 32;
    const int tx = threadIdx.x & 31, ty = threadIdx.x >> 5;   // ty 0..7
#pragma unroll
    for (int i = 0; i < 4; i++)
        t[ty + i * 8][tx] = W[(size_t)(k0 + ty + i * 8) * N + n0 + tx];
    __syncthreads();
#pragma unroll
    for (int i = 0; i < 4; i++)
        Wt[(size_t)(n0 + ty + i * 8) * K + k0 + tx] = f2bf(t[tx][ty + i * 8]);
}

// ---------- LayerNorm over C=1024, fp32 in -> bf16 out ----------
__global__ __launch_bounds__(256) void k_layernorm(
    const float* __restrict__ x, const float* __restrict__ g,
    const float* __restrict__ b, u16* __restrict__ out) {
    const int row = blockIdx.x, tid = threadIdx.x;
    float4 v = ((const float4*)x)[(size_t)row * 256 + tid];
    float s  = v.x + v.y + v.z + v.w;
    float s2 = v.x * v.x + v.y * v.y + v.z * v.z + v.w * v.w;
#pragma unroll
    for (int off = 32; off > 0; off >>= 1) {
        s  += __shfl_down(s, off);
        s2 += __shfl_down(s2, off);
    }
    __shared__ float rs[4], rs2[4];
    const int wv = tid >> 6;
    if ((tid & 63) == 0) { rs[wv] = s; rs2[wv] = s2; }
    __syncthreads();
    s  = rs[0] + rs[1] + rs[2] + rs[3];
    s2 = rs2[0] + rs2[1] + rs2[2] + rs2[3];
    const float mu  = s * (1.0f / 1024.0f);
    const float var = s2 * (1.0f / 1024.0f) - mu * mu;
    const float rstd = rsqrtf(var + 1e-5f);
    float4 gv = ((const float4*)g)[tid];
    float4 bv = ((const float4*)b)[tid];
    uint2 o;
    u16 a0 = f2bf((v.x - mu) * rstd * gv.x + bv.x);
    u16 a1 = f2bf((v.y - mu) * rstd * gv.y + bv.y);
    u16 a2 = f2bf((v.z - mu) * rstd * gv.z + bv.z);
    u16 a3 = f2bf((v.w - mu) * rstd * gv.w + bv.w);
    o.x = a0 | ((uint32_t)a1 << 16);
    o.y = a2 | ((uint32_t)a3 << 16);
    ((uint2*)out)[(size_t)row * 256 + tid] = o;
}

// ---------- bf16 GEMM: C[M,N] = A[M,K] * Bt[N,K]^T, fused epilogues ----------
// Split-K via blockIdx.z: each z-slice handles kPer of K; EPI_F32_ATOMIC
// accumulates into outp (which already holds the residual) with atomicAdd.
enum { EPI_BF16 = 0, EPI_F32_ATOMIC = 1, EPI_BF16_BIAS_GELU = 2 };

template <int EPI>
__global__ __launch_bounds__(256) void k_gemm_bt(
    const u16* __restrict__ A, const u16* __restrict__ Bt,
    void* outp, const float* __restrict__ bias,
    int N, int K, int kPer) {
    __shared__ __align__(16) u16 As[128 * 32];   // [row][swizzled k-chunk]
    __shared__ __align__(16) u16 Bs[128 * 32];
    const int tid  = threadIdx.x;
    const int lane = tid & 63, wv = tid >> 6;
    const int wm = wv >> 1, wn = wv & 1;          // 2x2 wave grid, 64x64 per wave
    const int lr = lane >> 2;
    // XOR swizzle: LDS slot q of row r holds global chunk q ^ ((r>>1)&3).
    // Applied on the GLOBAL address; lane->LDS mapping stays lane*16B.
    const int lc = ((lane & 3) ^ ((lane >> 3) & 3)) * 8;
    const int c0 = wv * 2;                        // LDS chunk index (16 rows / 1KB)
    const size_t aRow0 = (size_t)blockIdx.y * 128;
    const size_t bRow0 = (size_t)blockIdx.x * 128;
    const int ks = blockIdx.z;
    const int kBase = ks * kPer;

    f32x4 acc[4][4] = {};
    const int mrow = lane & 15;
    const int quad = lane >> 4;
    // fragment read offset, same swizzle: slot = quad ^ ((mrow>>1)&3)
    const int koff = ((quad ^ ((mrow >> 1) & 3)) << 3);
    const int kIters = kPer >> 5;

    for (int kt = 0; kt < kIters; kt++) {
        const int k0 = kBase + (kt << 5);
        gload_lds16(A  + (aRow0 + (size_t)(c0 * 16      + lr)) * K + k0 + lc, &As[c0 * 512]);
        gload_lds16(A  + (aRow0 + (size_t)(c0 * 16 + 16 + lr)) * K + k0 + lc, &As[(c0 + 1) * 512]);
        gload_lds16(Bt + (bRow0 + (size_t)(c0 * 16      + lr)) * K + k0 + lc, &Bs[c0 * 512]);
        gload_lds16(Bt + (bRow0 + (size_t)(c0 * 16 + 16 + lr)) * K + k0 + lc, &Bs[(c0 + 1) * 512]);
        __syncthreads();
        bf16x8 af[4], bfv[4];
#pragma unroll
        for (int i = 0; i < 4; i++)
            af[i] = *(const bf16x8*)&As[(wm * 64 + i * 16 + mrow) * 32 + koff];
#pragma unroll
        for (int i = 0; i < 4; i++)
            bfv[i] = *(const bf16x8*)&Bs[(wn * 64 + i * 16 + mrow) * 32 + koff];
#pragma unroll
        for (int mi = 0; mi < 4; mi++)
#pragma unroll
            for (int ni = 0; ni < 4; ni++)
                acc[mi][ni] = __builtin_amdgcn_mfma_f32_16x16x32_bf16(
                    af[mi], bfv[ni], acc[mi][ni], 0, 0, 0);
        __syncthreads();
    }

    // epilogue — C/D layout: col = lane&15, row = (lane>>4)*4 + reg
    const int rr = quad * 4;
    const int cc = mrow;
#pragma unroll
    for (int mi = 0; mi < 4; mi++) {
#pragma unroll
        for (int ni = 0; ni < 4; ni++) {
#pragma unroll
            for (int r = 0; r < 4; r++) {
                const size_t row = aRow0 + wm * 64 + mi * 16 + rr + r;
                const size_t col = bRow0 + wn * 64 + ni * 16 + cc;
                const float v = acc[mi][ni][r];
                if (EPI == EPI_BF16) {
                    ((u16*)outp)[row * N + col] = f2bf(v);
                } else if (EPI == EPI_F32_ATOMIC) {
                    const float add = (ks == 0) ? v + bias[col] : v;
                    atomicAdd(&((float*)outp)[row * N + col], add);
                } else {
                    ((u16*)outp)[row * N + col] = f2bf(gelu_exact(v + bias[col]));
                }
            }
        }
    }
}

// ---------- V transpose: qkv v-part [b,n,(h,d)] -> vT[(b,h),d,n] ----------
__global__ __launch_bounds__(256) void k_vtrans(
    const u16* __restrict__ qkv, u16* __restrict__ vT) {
    __shared__ u16 t[32][33];
    const int bh = blockIdx.z;                 // b*16+h
    const int b = bh >> 4, h = bh & 15;
    const int n0 = blockIdx.x * 32, d0 = blockIdx.y * 32;
    const int tx = threadIdx.x & 31, ty = threadIdx.x >> 5;
#pragma unroll
    for (int i = 0; i < 4; i++)
        t[ty + i * 8][tx] = qkv[(size_t)(b * 1024 + n0 + ty + i * 8) * 3072 + 2048 + h * 64 + d0 + tx];
    __syncthreads();
#pragma unroll
    for (int i = 0; i < 4; i++)
        vT[(size_t)(bh * 64 + d0 + ty + i * 8) * 1024 + n0 + tx] = t[tx][ty + i * 8];
}

// ---------- flash attention, bf16 MFMA, online softmax ----------
// grid (N/64, H, B); block 256 = 4 waves; each wave owns 16 q rows.
// Ks/Vs use XOR chunk swizzle (row stride 128B): slot chunk c of row r
// holds logical chunk c ^ (r&7). Ps padded to stride 72.
__global__ __launch_bounds__(256) void k_attention(
    const u16* __restrict__ qkv, const u16* __restrict__ vT, u16* __restrict__ o) {
    const int qt = blockIdx.x, h = blockIdx.y, b = blockIdx.z;
    const int tid = threadIdx.x;
    const int lane = tid & 63, wv = tid >> 6;
    const int quad = lane >> 4, l16 = lane & 15;
    __shared__ __align__(16) u16 Ks[64 * 64];      // [j][d] swizzled
    __shared__ __align__(16) u16 Vs[64 * 64];      // [d][j] swizzled
    __shared__ __align__(16) u16 Ps[4][16 * 72];   // per-wave P, padded stride
    const int q0 = qt * 64 + wv * 16;

    bf16x8 qa[2];
    {
        const u16* qp = qkv + (size_t)(b * 1024 + q0 + l16) * 3072 + h * 64 + quad * 8;
        qa[0] = *(const bf16x8*)qp;
        qa[1] = *(const bf16x8*)(qp + 32);
    }
    f32x4 oacc[4] = {};
    float mst[4], lst[4];
#pragma unroll
    for (int r = 0; r < 4; r++) { mst[r] = -__builtin_inff(); lst[r] = 0.f; }

    const int tr = tid >> 3, tc = tid & 7;        // staging: 32 rows x 8 chunks
    const int cs = (tc ^ (tr & 7)) * 8;           // swizzled LDS chunk offset
    const size_t kvbase = (size_t)(b * 1024) * 3072 + 1024 + h * 64;
    const size_t vtbase = (size_t)(b * 16 + h) * 64 * 1024;

    for (int j0 = 0; j0 < 1024; j0 += 64) {
        *(uint4*)&Ks[tr * 64 + cs]        = *(const uint4*)&qkv[kvbase + (size_t)(j0 + tr) * 3072 + tc * 8];
        *(uint4*)&Ks[(tr + 32) * 64 + cs] = *(const uint4*)&qkv[kvbase + (size_t)(j0 + tr + 32) * 3072 + tc * 8];
        *(uint4*)&Vs[tr * 64 + cs]        = *(const uint4*)&vT[vtbase + (size_t)tr * 1024 + j0 + tc * 8];
        *(uint4*)&Vs[(tr + 32) * 64 + cs] = *(const uint4*)&vT[vtbase + (size_t)(tr + 32) * 1024 + j0 + tc * 8];
        __syncthreads();

        // S = Q K^T  (16 qrows x 64 j per wave)
        f32x4 s[4] = {};
#pragma unroll
        for (int nt = 0; nt < 4; nt++) {
            const int rk = nt * 16 + l16;
            bf16x8 kb0 = *(const bf16x8*)&Ks[rk * 64 + ((quad ^ (rk & 7)) * 8)];
            bf16x8 kb1 = *(const bf16x8*)&Ks[rk * 64 + (((quad + 4) ^ (rk & 7)) * 8)];
            s[nt] = __builtin_amdgcn_mfma_f32_16x16x32_bf16(qa[0], kb0, s[nt], 0, 0, 0);
            s[nt] = __builtin_amdgcn_mfma_f32_16x16x32_bf16(qa[1], kb1, s[nt], 0, 0, 0);
        }
        // online softmax, rows quad*4+r, 16 lanes per row
#pragma unroll
        for (int r = 0; r < 4; r++) {
            float v0 = s[0][r] * 0.03125f, v1 = s[1][r] * 0.03125f;
            float v2 = s[2][r] * 0.03125f, v3 = s[3][r] * 0.03125f;
            float mx = fmaxf(fmaxf(v0, v1), fmaxf(v2, v3));
#pragma unroll
            for (int off = 1; off < 16; off <<= 1) mx = fmaxf(mx, __shfl_xor(mx, off));
            const float mnew = fmaxf(mst[r], mx);
            const float alpha = __expf(mst[r] - mnew);
            mst[r] = mnew;
            const float p0 = __expf(v0 - mnew), p1 = __expf(v1 - mnew);
            const float p2 = __expf(v2 - mnew), p3 = __expf(v3 - mnew);
            float rsum = p0 + p1 + p2 + p3;
#pragma unroll
            for (int off = 1; off < 16; off <<= 1) rsum += __shfl_xor(rsum, off);
            lst[r] = lst[r] * alpha + rsum;
#pragma unroll
            for (int dt = 0; dt < 4; dt++) oacc[dt][r] *= alpha;
            u16* pr = &Ps[wv][(quad * 4 + r) * 72 + l16];
            pr[0]  = f2bf(p0); pr[16] = f2bf(p1);
            pr[32] = f2bf(p2); pr[48] = f2bf(p3);
        }
        __syncthreads();
        // O += P V   (A = P via LDS round-trip, B = V from transposed tile)
        bf16x8 pa0 = *(const bf16x8*)&Ps[wv][l16 * 72 + quad * 8];
        bf16x8 pa1 = *(const bf16x8*)&Ps[wv][l16 * 72 + quad * 8 + 32];
#pragma unroll
        for (int dt = 0; dt < 4; dt++) {
            const int rv = dt * 16 + l16;
            bf16x8 vb0 = *(const bf16x8*)&Vs[rv * 64 + ((quad ^ (rv & 7)) * 8)];
            bf16x8 vb1 = *(const bf16x8*)&Vs[rv * 64 + (((quad + 4) ^ (rv & 7)) * 8)];
            oacc[dt] = __builtin_amdgcn_mfma_f32_16x16x32_bf16(pa0, vb0, oacc[dt], 0, 0, 0);
            oacc[dt] = __builtin_amdgcn_mfma_f32_16x16x32_bf16(pa1, vb1, oacc[dt], 0, 0, 0);
        }
        __syncthreads();
    }
#pragma unroll
    for (int dt = 0; dt < 4; dt++)
#pragma unroll
        for (int r = 0; r < 4; r++) {
            const float v = oacc[dt][r] / lst[r];
            o[(size_t)(b * 1024 + q0 + quad * 4 + r) * 1024 + h * 64 + dt * 16 + l16] = f2bf(v);
        }
}

// ---------- host ----------
extern "C" void kernel_launch(void* const* d_in, const int* in_sizes, int n_in,
                              void* d_out, int out_size, void* d_ws, size_t ws_size,
                              hipStream_t stream) {
    const float* x_in = (const float*)d_in[0];
    const float* Wqkv = (const float*)d_in[1];
    const float* Wout = (const float*)d_in[2];
    const float* bout = (const float*)d_in[3];
    const float* W1   = (const float*)d_in[4];
    const float* b1   = (const float*)d_in[5];
    const float* W2   = (const float*)d_in[6];
    const float* b2   = (const float*)d_in[7];
    const float* ln1g = (const float*)d_in[8];
    const float* ln1b = (const float*)d_in[9];
    const float* ln2g = (const float*)d_in[10];
    const float* ln2b = (const float*)d_in[11];
    float* xbuf = (float*)d_out;

    char* p = (char*)d_ws;
    auto carve = [&](size_t elems) -> u16* {
        u16* r = (u16*)p;
        p += ((elems * 2 + 255) & ~(size_t)255);
        return r;
    };
    u16* wq   = carve((size_t)3072 * 1024);   // per-layer Wqkv^T bf16
    u16* wo   = carve((size_t)1024 * 1024);   // per-layer Wout^T
    u16* w1t  = carve((size_t)4096 * 1024);   // per-layer W1^T
    u16* w2t  = carve((size_t)1024 * 4096);   // per-layer W2^T
    u16* hb   = carve((size_t)4096 * 1024);   // LN output bf16
    u16* qkvb = carve((size_t)4096 * 3072);   // qkv bf16
    u16* vtb  = carve((size_t)4096 * 1024);   // V^T bf16 [(b,h),d,n]
    u16* ob   = carve((size_t)4096 * 1024);   // attention out bf16
    u16* gb   = carve((size_t)4096 * 4096);   // gelu(ffn1) bf16
    if ((size_t)(p - (char*)d_ws) > ws_size) return;  // ws too small -> clean fail

    hipMemcpyAsync(xbuf, x_in, (size_t)4096 * 1024 * 4, hipMemcpyDeviceToDevice, stream);

    for (int l = 0; l < 6; l++) {
        k_transpose_conv<<<dim3(96, 32), 256, 0, stream>>>(Wqkv + (size_t)l * 1024 * 3072, wq, 1024, 3072);
        k_transpose_conv<<<dim3(32, 32), 256, 0, stream>>>(Wout + (size_t)l * 1024 * 1024, wo, 1024, 1024);
        k_transpose_conv<<<dim3(128, 32), 256, 0, stream>>>(W1 + (size_t)l * 1024 * 4096, w1t, 1024, 4096);
        k_transpose_conv<<<dim3(32, 128), 256, 0, stream>>>(W2 + (size_t)l * 4096 * 1024, w2t, 4096, 1024);

        k_layernorm<<<4096, 256, 0, stream>>>(xbuf, ln1g, ln1b, hb);
        k_gemm_bt<EPI_BF16><<<dim3(24, 32, 1), 256, 0, stream>>>(hb, wq, qkvb, nullptr, 3072, 1024, 1024);
        k_vtrans<<<dim3(32, 2, 64), 256, 0, stream>>>(qkvb, vtb);
        k_attention<<<dim3(16, 16, 4), 256, 0, stream>>>(qkvb, vtb, ob);
        // Wout: split-K=2, atomic accumulate into xbuf (residual already there)
        k_gemm_bt<EPI_F32_ATOMIC><<<dim3(8, 32, 2), 256, 0, stream>>>(ob, wo, xbuf, bout + (size_t)l * 1024, 1024, 1024, 512);
        k_layernorm<<<4096, 256, 0, stream>>>(xbuf, ln2g, ln2b, hb);
        k_gemm_bt<EPI_BF16_BIAS_GELU><<<dim3(32, 32, 1), 256, 0, stream>>>(hb, w1t, gb, b1 + (size_t)l * 4096, 4096, 1024, 1024);
        // W2: split-K=4, atomic accumulate into xbuf
        k_gemm_bt<EPI_F32_ATOMIC><<<dim3(8, 32, 4), 256, 0, stream>>>(gb, w2t, xbuf, b2 + (size_t)l * 1024, 1024, 4096, 1024);
    }
}

// Round 4
// 2040.785 us; speedup vs baseline: 1.1732x; 1.1056x over previous
//
#include <hip/hip_runtime.h>
#include <stdint.h>

typedef unsigned short u16;
typedef __bf16  bf16x8 __attribute__((ext_vector_type(8)));
typedef float   f32x4  __attribute__((ext_vector_type(4)));

#define DEVINL __device__ __forceinline__

// ---------- helpers ----------
DEVINL u16 f2bf(float f) {                       // RNE float->bf16
    union { float f; uint32_t u; } v; v.f = f;
    uint32_t r = v.u + 0x7fffu + ((v.u >> 16) & 1u);
    return (u16)(r >> 16);
}

DEVINL float gelu_exact(float x) {               // x * Phi(x), exact erf
    return 0.5f * x * (1.0f + erff(x * 0.70710678118654752f));
}

// async global->LDS, 16 B per lane. LDS dest must be wave-uniform base.
typedef const void __attribute__((address_space(1))) gvoid;
typedef void __attribute__((address_space(3))) lvoid;
DEVINL void gload_lds16(const u16* g, u16* l) {
    __builtin_amdgcn_global_load_lds((gvoid*)g, (lvoid*)l, 16, 0, 0);
}

// ---------- transpose + fp32->bf16 convert:  W[K][N] -> Wt[N][K] ----------
__global__ __launch_bounds__(256) void k_transpose_conv(
    const float* __restrict__ W, u16* __restrict__ Wt, int K, int N) {
    __shared__ float t[32][33];
    const int n0 = blockIdx.x * 32, k0 = blockIdx.y * 32;
    const int tx = threadIdx.x & 31, ty = threadIdx.x >> 5;   // ty 0..7
#pragma unroll
    for (int i = 0; i < 4; i++)
        t[ty + i * 8][tx] = W[(size_t)(k0 + ty + i * 8) * N + n0 + tx];
    __syncthreads();
#pragma unroll
    for (int i = 0; i < 4; i++)
        Wt[(size_t)(n0 + ty + i * 8) * K + k0 + tx] = f2bf(t[tx][ty + i * 8]);
}

// ---------- LayerNorm over C=1024, fp32 in -> bf16 out ----------
__global__ __launch_bounds__(256) void k_layernorm(
    const float* __restrict__ x, const float* __restrict__ g,
    const float* __restrict__ b, u16* __restrict__ out) {
    const int row = blockIdx.x, tid = threadIdx.x;
    float4 v = ((const float4*)x)[(size_t)row * 256 + tid];
    float s  = v.x + v.y + v.z + v.w;
    float s2 = v.x * v.x + v.y * v.y + v.z * v.z + v.w * v.w;
#pragma unroll
    for (int off = 32; off > 0; off >>= 1) {
        s  += __shfl_down(s, off);
        s2 += __shfl_down(s2, off);
    }
    __shared__ float rs[4], rs2[4];
    const int wv = tid >> 6;
    if ((tid & 63) == 0) { rs[wv] = s; rs2[wv] = s2; }
    __syncthreads();
    s  = rs[0] + rs[1] + rs[2] + rs[3];
    s2 = rs2[0] + rs2[1] + rs2[2] + rs2[3];
    const float mu  = s * (1.0f / 1024.0f);
    const float var = s2 * (1.0f / 1024.0f) - mu * mu;
    const float rstd = rsqrtf(var + 1e-5f);
    float4 gv = ((const float4*)g)[tid];
    float4 bv = ((const float4*)b)[tid];
    uint2 o;
    u16 a0 = f2bf((v.x - mu) * rstd * gv.x + bv.x);
    u16 a1 = f2bf((v.y - mu) * rstd * gv.y + bv.y);
    u16 a2 = f2bf((v.z - mu) * rstd * gv.z + bv.z);
    u16 a3 = f2bf((v.w - mu) * rstd * gv.w + bv.w);
    o.x = a0 | ((uint32_t)a1 << 16);
    o.y = a2 | ((uint32_t)a3 << 16);
    ((uint2*)out)[(size_t)row * 256 + tid] = o;
}

// ---------- bf16 GEMM: C[M,N] = A[M,K] * Bt[N,K]^T, fused epilogues ----------
// Double-buffered LDS, software-pipelined: tile t+1's global_load_lds stay in
// flight across the barrier (manual s_waitcnt vmcnt(4) waits only tile t).
enum { EPI_BF16 = 0, EPI_F32_ATOMIC = 1, EPI_BF16_BIAS_GELU = 2, EPI_F32_BIAS_RES = 3 };

template <int EPI>
__global__ __launch_bounds__(256) void k_gemm_bt(
    const u16* __restrict__ A, const u16* __restrict__ Bt,
    void* outp, const float* __restrict__ bias, const float* __restrict__ res,
    int N, int K, int kPer) {
    __shared__ __align__(16) u16 As[2][128 * 32];   // [buf][row][swizzled k-chunk]
    __shared__ __align__(16) u16 Bs[2][128 * 32];
    const int tid  = threadIdx.x;
    const int lane = tid & 63, wv = tid >> 6;
    const int wm = wv >> 1, wn = wv & 1;          // 2x2 wave grid, 64x64 per wave
    const int lr = lane >> 2;
    // XOR swizzle: LDS slot q of row r holds global chunk q ^ ((r>>1)&3).
    // Applied on the GLOBAL address; lane->LDS mapping stays lane*16B.
    const int lc = ((lane & 3) ^ ((lane >> 3) & 3)) * 8;
    const int c0 = wv * 2;                        // LDS chunk index (16 rows / 1KB)
    const size_t aRow0 = (size_t)blockIdx.y * 128;
    const size_t bRow0 = (size_t)blockIdx.x * 128;
    const int ks = blockIdx.z;
    const int kBase = ks * kPer;

    f32x4 acc[4][4] = {};
    const int mrow = lane & 15;
    const int quad = lane >> 4;
    // fragment read offset, same swizzle: slot = quad ^ ((mrow>>1)&3)
    const int koff = ((quad ^ ((mrow >> 1) & 3)) << 3);
    const int kIters = kPer >> 5;

    const u16* aP = A  + (aRow0 + (size_t)(c0 * 16 + lr)) * K + kBase + lc;
    const u16* bP = Bt + (bRow0 + (size_t)(c0 * 16 + lr)) * K + kBase + lc;
    const size_t rowStep = (size_t)16 * K;

    // stage tile 0 into buf 0
    gload_lds16(aP,           &As[0][c0 * 512]);
    gload_lds16(aP + rowStep, &As[0][(c0 + 1) * 512]);
    gload_lds16(bP,           &Bs[0][c0 * 512]);
    gload_lds16(bP + rowStep, &Bs[0][(c0 + 1) * 512]);

    for (int kt = 0; kt < kIters; kt++) {
        const int buf = kt & 1;
        if (kt + 1 < kIters) {
            const int k0 = (kt + 1) << 5;
            gload_lds16(aP + k0,           &As[buf ^ 1][c0 * 512]);
            gload_lds16(aP + k0 + rowStep, &As[buf ^ 1][(c0 + 1) * 512]);
            gload_lds16(bP + k0,           &Bs[buf ^ 1][c0 * 512]);
            gload_lds16(bP + k0 + rowStep, &Bs[buf ^ 1][(c0 + 1) * 512]);
            // wait only for tile kt's 4 loads; kt+1's stay in flight
            asm volatile("s_waitcnt vmcnt(4)\n\ts_barrier" ::: "memory");
        } else {
            asm volatile("s_waitcnt vmcnt(0)\n\ts_barrier" ::: "memory");
        }
        bf16x8 af[4], bfv[4];
#pragma unroll
        for (int i = 0; i < 4; i++)
            af[i] = *(const bf16x8*)&As[buf][(wm * 64 + i * 16 + mrow) * 32 + koff];
#pragma unroll
        for (int i = 0; i < 4; i++)
            bfv[i] = *(const bf16x8*)&Bs[buf][(wn * 64 + i * 16 + mrow) * 32 + koff];
#pragma unroll
        for (int mi = 0; mi < 4; mi++)
#pragma unroll
            for (int ni = 0; ni < 4; ni++)
                acc[mi][ni] = __builtin_amdgcn_mfma_f32_16x16x32_bf16(
                    af[mi], bfv[ni], acc[mi][ni], 0, 0, 0);
        // bare barrier: protect buf from being restaged next iter; no vm drain
        asm volatile("s_barrier" ::: "memory");
    }

    // epilogue — C/D layout: col = lane&15, row = (lane>>4)*4 + reg
    const int rr = quad * 4;
    const int cc = mrow;
#pragma unroll
    for (int mi = 0; mi < 4; mi++) {
#pragma unroll
        for (int ni = 0; ni < 4; ni++) {
#pragma unroll
            for (int r = 0; r < 4; r++) {
                const size_t row = aRow0 + wm * 64 + mi * 16 + rr + r;
                const size_t col = bRow0 + wn * 64 + ni * 16 + cc;
                const float v = acc[mi][ni][r];
                if (EPI == EPI_BF16) {
                    ((u16*)outp)[row * N + col] = f2bf(v);
                } else if (EPI == EPI_F32_ATOMIC) {
                    const float add = (ks == 0) ? v + bias[col] : v;
                    atomicAdd(&((float*)outp)[row * N + col], add);
                } else if (EPI == EPI_F32_BIAS_RES) {
                    ((float*)outp)[row * N + col] = res[row * N + col] + v + bias[col];
                } else {
                    ((u16*)outp)[row * N + col] = f2bf(gelu_exact(v + bias[col]));
                }
            }
        }
    }
}

// ---------- V transpose: qkv v-part [b,n,(h,d)] -> vT[(b,h),d,n] ----------
__global__ __launch_bounds__(256) void k_vtrans(
    const u16* __restrict__ qkv, u16* __restrict__ vT) {
    __shared__ u16 t[32][33];
    const int bh = blockIdx.z;                 // b*16+h
    const int b = bh >> 4, h = bh & 15;
    const int n0 = blockIdx.x * 32, d0 = blockIdx.y * 32;
    const int tx = threadIdx.x & 31, ty = threadIdx.x >> 5;
#pragma unroll
    for (int i = 0; i < 4; i++)
        t[ty + i * 8][tx] = qkv[(size_t)(b * 1024 + n0 + ty + i * 8) * 3072 + 2048 + h * 64 + d0 + tx];
    __syncthreads();
#pragma unroll
    for (int i = 0; i < 4; i++)
        vT[(size_t)(bh * 64 + d0 + ty + i * 8) * 1024 + n0 + tx] = t[tx][ty + i * 8];
}

// ---------- flash attention, bf16 MFMA, online softmax ----------
// grid (N/64, H, B); block 256 = 4 waves; each wave owns 16 q rows.
// Ks/Vs use XOR chunk swizzle (row stride 128B): slot chunk c of row r
// holds logical chunk c ^ (r&7). Ps padded to stride 72.
__global__ __launch_bounds__(256) void k_attention(
    const u16* __restrict__ qkv, const u16* __restrict__ vT, u16* __restrict__ o) {
    const int qt = blockIdx.x, h = blockIdx.y, b = blockIdx.z;
    const int tid = threadIdx.x;
    const int lane = tid & 63, wv = tid >> 6;
    const int quad = lane >> 4, l16 = lane & 15;
    __shared__ __align__(16) u16 Ks[64 * 64];      // [j][d] swizzled
    __shared__ __align__(16) u16 Vs[64 * 64];      // [d][j] swizzled
    __shared__ __align__(16) u16 Ps[4][16 * 72];   // per-wave P, padded stride
    const int q0 = qt * 64 + wv * 16;

    bf16x8 qa[2];
    {
        const u16* qp = qkv + (size_t)(b * 1024 + q0 + l16) * 3072 + h * 64 + quad * 8;
        qa[0] = *(const bf16x8*)qp;
        qa[1] = *(const bf16x8*)(qp + 32);
    }
    f32x4 oacc[4] = {};
    float mst[4], lst[4];
#pragma unroll
    for (int r = 0; r < 4; r++) { mst[r] = -__builtin_inff(); lst[r] = 0.f; }

    const int tr = tid >> 3, tc = tid & 7;        // staging: 32 rows x 8 chunks
    const int cs = (tc ^ (tr & 7)) * 8;           // swizzled LDS chunk offset
    const size_t kvbase = (size_t)(b * 1024) * 3072 + 1024 + h * 64;
    const size_t vtbase = (size_t)(b * 16 + h) * 64 * 1024;

    for (int j0 = 0; j0 < 1024; j0 += 64) {
        *(uint4*)&Ks[tr * 64 + cs]        = *(const uint4*)&qkv[kvbase + (size_t)(j0 + tr) * 3072 + tc * 8];
        *(uint4*)&Ks[(tr + 32) * 64 + cs] = *(const uint4*)&qkv[kvbase + (size_t)(j0 + tr + 32) * 3072 + tc * 8];
        *(uint4*)&Vs[tr * 64 + cs]        = *(const uint4*)&vT[vtbase + (size_t)tr * 1024 + j0 + tc * 8];
        *(uint4*)&Vs[(tr + 32) * 64 + cs] = *(const uint4*)&vT[vtbase + (size_t)(tr + 32) * 1024 + j0 + tc * 8];
        __syncthreads();

        // S = Q K^T  (16 qrows x 64 j per wave)
        f32x4 s[4] = {};
#pragma unroll
        for (int nt = 0; nt < 4; nt++) {
            const int rk = nt * 16 + l16;
            bf16x8 kb0 = *(const bf16x8*)&Ks[rk * 64 + ((quad ^ (rk & 7)) * 8)];
            bf16x8 kb1 = *(const bf16x8*)&Ks[rk * 64 + (((quad + 4) ^ (rk & 7)) * 8)];
            s[nt] = __builtin_amdgcn_mfma_f32_16x16x32_bf16(qa[0], kb0, s[nt], 0, 0, 0);
            s[nt] = __builtin_amdgcn_mfma_f32_16x16x32_bf16(qa[1], kb1, s[nt], 0, 0, 0);
        }
        // online softmax, rows quad*4+r, 16 lanes per row
#pragma unroll
        for (int r = 0; r < 4; r++) {
            float v0 = s[0][r] * 0.03125f, v1 = s[1][r] * 0.03125f;
            float v2 = s[2][r] * 0.03125f, v3 = s[3][r] * 0.03125f;
            float mx = fmaxf(fmaxf(v0, v1), fmaxf(v2, v3));
#pragma unroll
            for (int off = 1; off < 16; off <<= 1) mx = fmaxf(mx, __shfl_xor(mx, off));
            const float mnew = fmaxf(mst[r], mx);
            const float alpha = __expf(mst[r] - mnew);
            mst[r] = mnew;
            const float p0 = __expf(v0 - mnew), p1 = __expf(v1 - mnew);
            const float p2 = __expf(v2 - mnew), p3 = __expf(v3 - mnew);
            float rsum = p0 + p1 + p2 + p3;
#pragma unroll
            for (int off = 1; off < 16; off <<= 1) rsum += __shfl_xor(rsum, off);
            lst[r] = lst[r] * alpha + rsum;
#pragma unroll
            for (int dt = 0; dt < 4; dt++) oacc[dt][r] *= alpha;
            u16* pr = &Ps[wv][(quad * 4 + r) * 72 + l16];
            pr[0]  = f2bf(p0); pr[16] = f2bf(p1);
            pr[32] = f2bf(p2); pr[48] = f2bf(p3);
        }
        __syncthreads();
        // O += P V   (A = P via LDS round-trip, B = V from transposed tile)
        bf16x8 pa0 = *(const bf16x8*)&Ps[wv][l16 * 72 + quad * 8];
        bf16x8 pa1 = *(const bf16x8*)&Ps[wv][l16 * 72 + quad * 8 + 32];
#pragma unroll
        for (int dt = 0; dt < 4; dt++) {
            const int rv = dt * 16 + l16;
            bf16x8 vb0 = *(const bf16x8*)&Vs[rv * 64 + ((quad ^ (rv & 7)) * 8)];
            bf16x8 vb1 = *(const bf16x8*)&Vs[rv * 64 + (((quad + 4) ^ (rv & 7)) * 8)];
            oacc[dt] = __builtin_amdgcn_mfma_f32_16x16x32_bf16(pa0, vb0, oacc[dt], 0, 0, 0);
            oacc[dt] = __builtin_amdgcn_mfma_f32_16x16x32_bf16(pa1, vb1, oacc[dt], 0, 0, 0);
        }
        __syncthreads();
    }
#pragma unroll
    for (int dt = 0; dt < 4; dt++)
#pragma unroll
        for (int r = 0; r < 4; r++) {
            const float v = oacc[dt][r] / lst[r];
            o[(size_t)(b * 1024 + q0 + quad * 4 + r) * 1024 + h * 64 + dt * 16 + l16] = f2bf(v);
        }
}

// ---------- host ----------
extern "C" void kernel_launch(void* const* d_in, const int* in_sizes, int n_in,
                              void* d_out, int out_size, void* d_ws, size_t ws_size,
                              hipStream_t stream) {
    const float* x_in = (const float*)d_in[0];
    const float* Wqkv = (const float*)d_in[1];
    const float* Wout = (const float*)d_in[2];
    const float* bout = (const float*)d_in[3];
    const float* W1   = (const float*)d_in[4];
    const float* b1   = (const float*)d_in[5];
    const float* W2   = (const float*)d_in[6];
    const float* b2   = (const float*)d_in[7];
    const float* ln1g = (const float*)d_in[8];
    const float* ln1b = (const float*)d_in[9];
    const float* ln2g = (const float*)d_in[10];
    const float* ln2b = (const float*)d_in[11];
    float* xbuf = (float*)d_out;

    char* p = (char*)d_ws;
    auto carve = [&](size_t elems) -> u16* {
        u16* r = (u16*)p;
        p += ((elems * 2 + 255) & ~(size_t)255);
        return r;
    };
    u16* wq   = carve((size_t)3072 * 1024);   // per-layer Wqkv^T bf16
    u16* wo   = carve((size_t)1024 * 1024);   // per-layer Wout^T
    u16* w1t  = carve((size_t)4096 * 1024);   // per-layer W1^T
    u16* w2t  = carve((size_t)1024 * 4096);   // per-layer W2^T
    u16* hb   = carve((size_t)4096 * 1024);   // LN output bf16
    u16* qkvb = carve((size_t)4096 * 3072);   // qkv bf16
    u16* vtb  = carve((size_t)4096 * 1024);   // V^T bf16 [(b,h),d,n]
    u16* ob   = carve((size_t)4096 * 1024);   // attention out bf16
    u16* gb   = carve((size_t)4096 * 4096);   // gelu(ffn1) bf16
    if ((size_t)(p - (char*)d_ws) > ws_size) return;  // ws too small -> clean fail

    hipMemcpyAsync(xbuf, x_in, (size_t)4096 * 1024 * 4, hipMemcpyDeviceToDevice, stream);

    for (int l = 0; l < 6; l++) {
        k_transpose_conv<<<dim3(96, 32), 256, 0, stream>>>(Wqkv + (size_t)l * 1024 * 3072, wq, 1024, 3072);
        k_transpose_conv<<<dim3(32, 32), 256, 0, stream>>>(Wout + (size_t)l * 1024 * 1024, wo, 1024, 1024);
        k_transpose_conv<<<dim3(128, 32), 256, 0, stream>>>(W1 + (size_t)l * 1024 * 4096, w1t, 1024, 4096);
        k_transpose_conv<<<dim3(32, 128), 256, 0, stream>>>(W2 + (size_t)l * 4096 * 1024, w2t, 4096, 1024);

        k_layernorm<<<4096, 256, 0, stream>>>(xbuf, ln1g, ln1b, hb);
        k_gemm_bt<EPI_BF16><<<dim3(24, 32, 1), 256, 0, stream>>>(hb, wq, qkvb, nullptr, nullptr, 3072, 1024, 1024);
        k_vtrans<<<dim3(32, 2, 64), 256, 0, stream>>>(qkvb, vtb);
        k_attention<<<dim3(16, 16, 4), 256, 0, stream>>>(qkvb, vtb, ob);
        // Wout: no split-K; fused bias + residual read (res == outp, disjoint elems)
        k_gemm_bt<EPI_F32_BIAS_RES><<<dim3(8, 32, 1), 256, 0, stream>>>(ob, wo, xbuf, bout + (size_t)l * 1024, xbuf, 1024, 1024, 1024);
        k_layernorm<<<4096, 256, 0, stream>>>(xbuf, ln2g, ln2b, hb);
        k_gemm_bt<EPI_BF16_BIAS_GELU><<<dim3(32, 32, 1), 256, 0, stream>>>(hb, w1t, gb, b1 + (size_t)l * 4096, nullptr, 4096, 1024, 1024);
        // W2: split-K=2, atomic accumulate into xbuf (residual already there)
        k_gemm_bt<EPI_F32_ATOMIC><<<dim3(8, 32, 2), 256, 0, stream>>>(gb, w2t, xbuf, b2 + (size_t)l * 1024, nullptr, 1024, 4096, 2048);
    }
}